// Round 1
// baseline (235.846 us; speedup 1.0000x reference)
//
#include <hip/hip_runtime.h>
#include <math.h>

#define NQ 6
#define DIM 64
#define PI_F 3.14159265358979323846f

// Apply one StronglyEntanglingLayer: Rot on each wire (coeffs from LDS), then
// CNOT ring with range R. All state indices compile-time constant.
template <int R>
__device__ __forceinline__ void apply_layer(float (&re)[64], float (&im)[64],
                                            const float4* __restrict__ cf) {
  #pragma unroll
  for (int w = 0; w < NQ; ++w) {
    float4 c = cf[w];          // LDS broadcast read (same addr all lanes)
    float ar = c.x, ai = c.y, br = c.z, bi = c.w;
    const int mask = 32 >> w;  // wire w <-> bit (5-w)
    #pragma unroll
    for (int i0 = 0; i0 < 64; ++i0) {
      if (i0 & mask) continue;
      const int i1 = i0 | mask;
      float p0r = re[i0], p0i = im[i0];
      float p1r = re[i1], p1i = im[i1];
      // U = [[a, b], [-conj(b), conj(a)]]
      re[i0] = ar*p0r - ai*p0i + br*p1r - bi*p1i;
      im[i0] = ar*p0i + ai*p0r + br*p1i + bi*p1r;
      re[i1] = -br*p0r - bi*p0i + ar*p1r + ai*p1i;
      im[i1] = -br*p0i + bi*p0r + ar*p1i - ai*p1r;
    }
  }
  // CNOT ring: control w, target (w+R)%6, sequential in w
  #pragma unroll
  for (int w = 0; w < NQ; ++w) {
    const int tq = (w + R) % NQ;
    const int cm = 32 >> w;
    const int tm = 32 >> tq;
    #pragma unroll
    for (int i = 0; i < 64; ++i) {
      if ((i & cm) && !(i & tm)) {
        const int j = i | tm;
        float tr = re[i]; re[i] = re[j]; re[j] = tr;
        float ti = im[i]; im[i] = im[j]; im[j] = ti;
      }
    }
  }
}

__global__ __launch_bounds__(256, 1) void qmaml_fused(
    const float* __restrict__ x,
    const float* __restrict__ W1,
    const float* __restrict__ b1,
    const float* __restrict__ ln_g,
    const float* __restrict__ ln_b,
    const float* __restrict__ W2,
    const float* __restrict__ b2,
    const float* __restrict__ th_sh,   // (2,6,3)
    const float* __restrict__ th_tk,   // (1,6,3)
    const float* __restrict__ Wc,      // (5,6)
    const float* __restrict__ bc,      // (5,)
    float* __restrict__ out,           // (B,5)
    int B)
{
  // ---- per-block gate coefficient table (batch independent) ----
  __shared__ float4 coef[18];
  const int tid = threadIdx.x;
  if (tid < 18) {
    const int layer = tid / 6, w = tid % 6;
    const float* th = (layer < 2) ? (th_sh + (layer * 6 + w) * 3)
                                  : (th_tk + w * 3);
    const float phi = th[0], the = th[1], om = th[2];
    float S, C;   sincosf(0.5f * the,        &S,  &C);
    float sS, cS; sincosf(0.5f * (om + phi), &sS, &cS);
    float sD, cD; sincosf(0.5f * (om - phi), &sD, &cD);
    // a = C e^{-i(om+phi)/2},  b = -S e^{-i(om-phi)/2}
    coef[tid] = make_float4(C * cS, -C * sS, -S * cD, S * sD);
  }
  __syncthreads();

  const int t = blockIdx.x * blockDim.x + tid;
  if (t >= B) return;

  // ---- encoder: Linear -> ReLU -> LayerNorm -> Linear -> tanh ----
  float xv[DIM];
  {
    const float4* xr = reinterpret_cast<const float4*>(x + (size_t)t * DIM);
    #pragma unroll
    for (int k4 = 0; k4 < DIM / 4; ++k4) {
      float4 v = xr[k4];
      xv[4 * k4 + 0] = v.x; xv[4 * k4 + 1] = v.y;
      xv[4 * k4 + 2] = v.z; xv[4 * k4 + 3] = v.w;
    }
  }

  float h[DIM];
  #pragma unroll
  for (int j = 0; j < DIM; ++j) {
    float acc = b1[j];
    const float* wr = W1 + j * DIM;   // uniform address -> s_load expected
    #pragma unroll
    for (int k = 0; k < DIM; ++k) acc = fmaf(wr[k], xv[k], acc);
    h[j] = fmaxf(acc, 0.0f);
  }

  float mu = 0.0f;
  #pragma unroll
  for (int j = 0; j < DIM; ++j) mu += h[j];
  mu *= (1.0f / DIM);
  float var = 0.0f;
  #pragma unroll
  for (int j = 0; j < DIM; ++j) { float d = h[j] - mu; var = fmaf(d, d, var); }
  var *= (1.0f / DIM);
  const float rs = 1.0f / sqrtf(var + 1e-5f);
  #pragma unroll
  for (int j = 0; j < DIM; ++j)
    h[j] = (h[j] - mu) * rs * ln_g[j] + ln_b[j];

  float cw[NQ], sw[NQ];
  #pragma unroll
  for (int m = 0; m < NQ; ++m) {
    float acc = b2[m];
    const float* wr = W2 + m * DIM;
    #pragma unroll
    for (int k = 0; k < DIM; ++k) acc = fmaf(wr[k], h[k], acc);
    const float z = tanhf(acc);
    sincosf(0.5f * PI_F * z, &sw[m], &cw[m]);  // half-angle of RY(pi*z)
  }

  // ---- quantum state-vector sim, state fully in registers ----
  float re[64], im[64];
  #pragma unroll
  for (int i = 0; i < 64; ++i) {
    float a = (i & 32) ? sw[0] : cw[0];
    a *= (i & 16) ? sw[1] : cw[1];
    a *= (i &  8) ? sw[2] : cw[2];
    a *= (i &  4) ? sw[3] : cw[3];
    a *= (i &  2) ? sw[4] : cw[4];
    a *= (i &  1) ? sw[5] : cw[5];
    re[i] = a;
    im[i] = 0.0f;   // compile-time zero -> first layer folds
  }

  apply_layer<1>(re, im, coef + 0);   // theta_shared l=0, r=1
  apply_layer<2>(re, im, coef + 6);   // theta_shared l=1, r=2
  apply_layer<1>(re, im, coef + 12);  // theta_task   l=0, r=1

  // ---- <Z_w> and classifier head ----
  float q[NQ] = {0.f, 0.f, 0.f, 0.f, 0.f, 0.f};
  #pragma unroll
  for (int i = 0; i < 64; ++i) {
    const float p = fmaf(re[i], re[i], im[i] * im[i]);
    #pragma unroll
    for (int w = 0; w < NQ; ++w) q[w] += (i & (32 >> w)) ? -p : p;
  }

  #pragma unroll
  for (int j = 0; j < 5; ++j) {
    float acc = bc[j];
    #pragma unroll
    for (int w = 0; w < NQ; ++w) acc = fmaf(Wc[j * NQ + w], q[w], acc);
    out[(size_t)t * 5 + j] = acc;
  }
}

extern "C" void kernel_launch(void* const* d_in, const int* in_sizes, int n_in,
                              void* d_out, int out_size, void* d_ws, size_t ws_size,
                              hipStream_t stream) {
  const float* x     = (const float*)d_in[0];
  const float* W1    = (const float*)d_in[1];
  const float* b1    = (const float*)d_in[2];
  const float* ln_g  = (const float*)d_in[3];
  const float* ln_b  = (const float*)d_in[4];
  const float* W2    = (const float*)d_in[5];
  const float* b2    = (const float*)d_in[6];
  const float* th_sh = (const float*)d_in[7];
  const float* th_tk = (const float*)d_in[8];
  const float* Wc    = (const float*)d_in[9];
  const float* bc    = (const float*)d_in[10];
  float* out = (float*)d_out;

  const int B = in_sizes[0] / DIM;
  const int block = 256;
  const int grid = (B + block - 1) / block;
  qmaml_fused<<<grid, block, 0, stream>>>(x, W1, b1, ln_g, ln_b, W2, b2,
                                          th_sh, th_tk, Wc, bc, out, B);
}

// Round 2
// 64.606 us; speedup vs baseline: 3.6505x; 3.6505x over previous
//
#include <hip/hip_runtime.h>
#include <math.h>

#define NQ 6
#define DIM 64
#define W1S 65           // padded LDS stride
#define PI_F 3.14159265358979323846f

// ---------- DPP helpers ----------
template <int CTRL, int ROWM, bool BC>
__device__ __forceinline__ float dpp_add_src(float v) {
  int r = __builtin_amdgcn_update_dpp(0, __float_as_int(v), CTRL, ROWM, 0xF, BC);
  return __int_as_float(r);
}

// sum over 64 lanes; valid in lane 63
__device__ __forceinline__ float red_sum(float v) {
  v += dpp_add_src<0x111, 0xF, true>(v);   // row_shr:1
  v += dpp_add_src<0x112, 0xF, true>(v);   // row_shr:2
  v += dpp_add_src<0x114, 0xF, true>(v);   // row_shr:4
  v += dpp_add_src<0x118, 0xF, true>(v);   // row_shr:8
  v += dpp_add_src<0x142, 0xA, false>(v);  // row_bcast:15 -> rows 1,3
  v += dpp_add_src<0x143, 0xC, false>(v);  // row_bcast:31 -> rows 2,3
  return v;
}
__device__ __forceinline__ float bcast63(float v) {
  return __int_as_float(__builtin_amdgcn_readlane(__float_as_int(v), 63));
}
__device__ __forceinline__ float rdlane(float v, int l) {
  return __int_as_float(__builtin_amdgcn_readlane(__float_as_int(v), l));
}

// ---------- xor-partner shuffle for wire W (mask = 32>>W) ----------
template <int W>
__device__ __forceinline__ float sh_partner(float v) {
  if constexpr (W == 5) {        // xor 1: quad_perm [1,0,3,2]
    int i = __float_as_int(v);
    return __int_as_float(__builtin_amdgcn_update_dpp(i, i, 0xB1, 0xF, 0xF, false));
  } else if constexpr (W == 4) { // xor 2: quad_perm [2,3,0,1]
    int i = __float_as_int(v);
    return __int_as_float(__builtin_amdgcn_update_dpp(i, i, 0x4E, 0xF, 0xF, false));
  } else if constexpr (W == 3) { // xor 4
    return __int_as_float(__builtin_amdgcn_ds_swizzle(__float_as_int(v), 0x101F));
  } else if constexpr (W == 2) { // xor 8
    return __int_as_float(__builtin_amdgcn_ds_swizzle(__float_as_int(v), 0x201F));
  } else if constexpr (W == 1) { // xor 16
    return __int_as_float(__builtin_amdgcn_ds_swizzle(__float_as_int(v), 0x401F));
  } else {                       // xor 32
    return __shfl_xor(v, 32, 64);
  }
}

// ---------- one Rot gate on wire W; c = (ar, ai, br, bi) ----------
template <int W>
__device__ __forceinline__ void gate_w(float& re, float& im, float4 c, int lane) {
  float pr = sh_partner<W>(re);
  float pi = sh_partner<W>(im);
  const bool hi = (lane & (32 >> W)) != 0;
  float sa = hi ? -c.y : c.y;
  float sb = hi ? -c.z : c.z;
  float nr = c.x * re;
  nr = fmaf(-sa, im, nr);
  nr = fmaf(sb, pr, nr);
  nr = fmaf(-c.w, pi, nr);
  float ni = c.x * im;
  ni = fmaf(sa, re, ni);
  ni = fmaf(sb, pi, ni);
  ni = fmaf(c.w, pr, ni);
  re = nr; im = ni;
}

__device__ __forceinline__ void sel_layer(float& re, float& im,
                                          const float4* cf, int pa, int lane) {
  gate_w<0>(re, im, cf[0], lane);
  gate_w<1>(re, im, cf[1], lane);
  gate_w<2>(re, im, cf[2], lane);
  gate_w<3>(re, im, cf[3], lane);
  gate_w<4>(re, im, cf[4], lane);
  gate_w<5>(re, im, cf[5], lane);
  re = __int_as_float(__builtin_amdgcn_ds_bpermute(pa, __float_as_int(re)));
  im = __int_as_float(__builtin_amdgcn_ds_bpermute(pa, __float_as_int(im)));
}

// composed source index for the CNOT ring of range r: src = C0(C1(...C5(j)))
__device__ __forceinline__ int cnot_src(int j, int r) {
  int i = j;
  #pragma unroll
  for (int w = 5; w >= 0; --w) {
    const int cm = 32 >> w;
    const int tm = 32 >> ((w + r) % NQ);
    if (i & cm) i ^= tm;
  }
  return i;
}

__global__ __launch_bounds__(256) void qmaml_wave(
    const float* __restrict__ x,
    const float* __restrict__ W1,
    const float* __restrict__ b1,
    const float* __restrict__ ln_g,
    const float* __restrict__ ln_b,
    const float* __restrict__ W2,
    const float* __restrict__ b2,
    const float* __restrict__ th_sh,
    const float* __restrict__ th_tk,
    const float* __restrict__ Wc,
    const float* __restrict__ bc,
    float* __restrict__ out,
    int B)
{
  __shared__ float w1t[64 * W1S];   // W1^T padded: w1t[k*65 + j] = W1[j][k]
  __shared__ float4 coef[18];

  const int tid = threadIdx.x;

  // ---- stage W1^T (coalesced global reads, conflict-free LDS writes) ----
  #pragma unroll
  for (int it = 0; it < 16; ++it) {
    int idx = tid + it * 256;
    int j = idx >> 6, k = idx & 63;
    w1t[k * W1S + j] = W1[idx];
  }
  // ---- gate coefficient table ----
  if (tid < 18) {
    const int layer = tid / 6, w = tid % 6;
    const float* th = (layer < 2) ? (th_sh + (layer * 6 + w) * 3)
                                  : (th_tk + w * 3);
    const float phi = th[0], the = th[1], om = th[2];
    float S, C;   sincosf(0.5f * the,        &S,  &C);
    float sS, cS; sincosf(0.5f * (om + phi), &sS, &cS);
    float sD, cD; sincosf(0.5f * (om - phi), &sD, &cD);
    coef[tid] = make_float4(C * cS, -C * sS, -S * cD, S * sD);
  }
  __syncthreads();

  const int lane = tid & 63;
  const int gw = blockIdx.x * 4 + (tid >> 6);
  const int nw = gridDim.x * 4;

  // ---- batch-independent per-lane preloads ----
  const float b1v = b1[lane];
  const float lgv = ln_g[lane];
  const float lbv = ln_b[lane];
  float w2v[NQ];
  #pragma unroll
  for (int m = 0; m < NQ; ++m) w2v[m] = W2[m * DIM + lane];
  const float b2v = (lane < NQ) ? b2[lane] : 0.0f;
  const float bcv = (lane < 5) ? bc[lane] : 0.0f;
  float g[5];
  #pragma unroll
  for (int j = 0; j < 5; ++j) {
    float a = 0.0f;
    #pragma unroll
    for (int w = 0; w < NQ; ++w) {
      float wc = Wc[j * NQ + w];
      a += (lane & (32 >> w)) ? -wc : wc;
    }
    g[j] = a;
  }
  const int pa1 = cnot_src(lane, 1) << 2;
  const int pa2 = cnot_src(lane, 2) << 2;

  for (int t = gw; t < B; t += nw) {
    // x row is wave-uniform -> force scalar (SMEM) loads
    const float* __restrict__ xr =
        x + (size_t)__builtin_amdgcn_readfirstlane(t) * DIM;

    // ---- Linear1 + ReLU: lane j computes h_j ----
    float acc = b1v;
    #pragma unroll
    for (int k = 0; k < DIM; ++k)
      acc = fmaf(w1t[k * W1S + lane], xr[k], acc);
    float h = fmaxf(acc, 0.0f);

    // ---- LayerNorm across lanes ----
    const float mu = bcast63(red_sum(h)) * (1.0f / DIM);
    const float d = h - mu;
    const float var = bcast63(red_sum(d * d)) * (1.0f / DIM);
    const float rs = __builtin_amdgcn_rsqf(var + 1e-5f);
    h = fmaf(d * rs, lgv, lbv);

    // ---- Linear2: angle accumulators land in lanes 0..5 ----
    float y = 0.0f;
    #pragma unroll
    for (int m = 0; m < NQ; ++m) {
      float r = bcast63(red_sum(w2v[m] * h));
      y = (lane == m) ? r : y;
    }
    y += b2v;

    // ---- tanh + half-angle sincos (lane-parallel, once) ----
    const float e = __expf(2.0f * y);
    const float tz = fmaf(-2.0f, __builtin_amdgcn_rcpf(e + 1.0f), 1.0f);
    const float ha = (0.5f * PI_F) * tz;      // (pi*z)/2
    const float sv = __sinf(ha);
    const float cv = __cosf(ha);
    float s[NQ], c[NQ];
    #pragma unroll
    for (int w = 0; w < NQ; ++w) { s[w] = rdlane(sv, w); c[w] = rdlane(cv, w); }

    // ---- init product state: lane = basis index ----
    float re = (lane & 32) ? s[0] : c[0];
    re *= (lane & 16) ? s[1] : c[1];
    re *= (lane &  8) ? s[2] : c[2];
    re *= (lane &  4) ? s[3] : c[3];
    re *= (lane &  2) ? s[4] : c[4];
    re *= (lane &  1) ? s[5] : c[5];
    float im = 0.0f;

    // ---- 3 entangling layers (r = 1, 2, 1) ----
    sel_layer(re, im, coef + 0,  pa1, lane);
    sel_layer(re, im, coef + 6,  pa2, lane);
    sel_layer(re, im, coef + 12, pa1, lane);

    // ---- measurement + classifier head ----
    const float p = fmaf(re, re, im * im);
    float o0 = bcast63(red_sum(p * g[0]));
    float o1 = bcast63(red_sum(p * g[1]));
    float o2 = bcast63(red_sum(p * g[2]));
    float o3 = bcast63(red_sum(p * g[3]));
    float o4 = bcast63(red_sum(p * g[4]));
    float vout = (lane == 0) ? o0 :
                 (lane == 1) ? o1 :
                 (lane == 2) ? o2 :
                 (lane == 3) ? o3 : o4;
    if (lane < 5) out[(size_t)t * 5 + lane] = vout + bcv;
  }
}

extern "C" void kernel_launch(void* const* d_in, const int* in_sizes, int n_in,
                              void* d_out, int out_size, void* d_ws, size_t ws_size,
                              hipStream_t stream) {
  const float* x     = (const float*)d_in[0];
  const float* W1    = (const float*)d_in[1];
  const float* b1    = (const float*)d_in[2];
  const float* ln_g  = (const float*)d_in[3];
  const float* ln_b  = (const float*)d_in[4];
  const float* W2    = (const float*)d_in[5];
  const float* b2    = (const float*)d_in[6];
  const float* th_sh = (const float*)d_in[7];
  const float* th_tk = (const float*)d_in[8];
  const float* Wc    = (const float*)d_in[9];
  const float* bc    = (const float*)d_in[10];
  float* out = (float*)d_out;

  const int B = in_sizes[0] / DIM;
  int blocks = (B + 3) / 4;          // 4 waves (elements) per block minimum
  if (blocks > 2048) blocks = 2048;  // 8 blocks/CU, grid-stride the rest
  qmaml_wave<<<blocks, 256, 0, stream>>>(x, W1, b1, ln_g, ln_b, W2, b2,
                                         th_sh, th_tk, Wc, bc, out, B);
}